// Round 4
// baseline (117.619 us; speedup 1.0000x reference)
//
#include <hip/hip_runtime.h>
#include <stdint.h>
#include <math.h>

#define BB 256
#define ROW 128000
#define SPLIT 5
#define CHUNK (ROW / SPLIT)        // 25600
#define THREADS 640                // 10 waves
#define WAVES (THREADS / 64)
#define ITERS 5                    // 640 * 8 * 5 = 25600 exactly -> no tail
#define GRID (BB * SPLIT)          // 1280 blocks

#define TF_K2 0x1BD11BF0u          // 0x1BD11BDA ^ 0 ^ 42

__device__ __forceinline__ uint32_t rotl32(uint32_t x, int r) {
    return __builtin_amdgcn_alignbit(x, x, 32 - r);  // v_alignbit_b32
}

// Threefry-2x32, key=(0,42), counter (0, c+j) for j=0..7, output o0^o1
// (JAX partitionable threefry — verified bit-exact, absmax 0.0 in R1-R3).
// Structured so injections fold into v_add3_u32 and round 1 uses x0_init=0.
__device__ __forceinline__ void threefry8_xor(uint32_t c, uint32_t bits[8]) {
    uint32_t x0[8], x1[8];
#pragma unroll
    for (int j = 0; j < 8; ++j) x1[j] = c + (uint32_t)j + 42u;

    // round 1: x0 = 0 + x1
#pragma unroll
    for (int j = 0; j < 8; ++j) {
        x0[j] = x1[j];
        x1[j] = rotl32(x1[j], 13) ^ x0[j];
    }

#define RND(r)                                        \
    do {                                              \
        _Pragma("unroll")                             \
        for (int j = 0; j < 8; ++j) {                 \
            x0[j] += x1[j];                           \
            x1[j] = rotl32(x1[j], (r)) ^ x0[j];       \
        }                                             \
    } while (0)
// injected round: x1 += B; x0 = x0 + A + x1 (v_add3); then rotate/xor
#define RNDI(r, A, B)                                 \
    do {                                              \
        _Pragma("unroll")                             \
        for (int j = 0; j < 8; ++j) {                 \
            x1[j] += (B);                             \
            x0[j] = x0[j] + (A) + x1[j];              \
            x1[j] = rotl32(x1[j], (r)) ^ x0[j];       \
        }                                             \
    } while (0)

    RND(15); RND(26); RND(6);
    RNDI(17, 42u, TF_K2 + 1u);
    RND(29); RND(16); RND(24);
    RNDI(13, TF_K2, 2u);
    RND(15); RND(26); RND(6);
    RNDI(17, 0u, 45u);
    RND(29); RND(16); RND(24);
    RNDI(13, 42u, TF_K2 + 4u);
    RND(15); RND(26); RND(6);

#undef RND
#undef RNDI

#pragma unroll
    for (int j = 0; j < 8; ++j) bits[j] = (x0[j] + TF_K2) ^ (x1[j] + 5u);
}

// order-preserving float -> uint32 map (final reduction only)
__device__ __forceinline__ uint32_t f2o(float f) {
    uint32_t u = __float_as_uint(f);
    return (u & 0x80000000u) ? ~u : (u | 0x80000000u);
}

// -ln(E), E = max(-log1p(-u), 1e-10), u = (bits>>9)*2^-23 exactly.
// Series path for u < 2^-5 protects hw-log relative precision near m=1
// (winners live at tiny u -> large -lnE; this must stay accurate).
__device__ __forceinline__ float neg_log_exp_noise(uint32_t bits) {
    const float uf = __uint_as_float(0x3F800000u | (bits >> 9));  // 1+u
    const float u = uf - 1.0f;   // exact
    const float m = 2.0f - uf;   // exact 1-u
    const float lg_m = __builtin_amdgcn_logf(m);       // log2(1-u), quarter-rate
    const float E_main = -0.69314718055994530942f * lg_m;
    // 4-term series, u < 2^-5: rel err ~u^4/5 < 2e-7
    const float E_ser =
        u * fmaf(u, fmaf(u, fmaf(u, 0.25f, 0.33333333333f), 0.5f), 1.0f);
    float E = (u < 0.03125f) ? E_ser : E_main;
    E = fmaxf(E, 1e-10f);  // only u==0 hits this (matches ref clamp)
    return -0.69314718055994530942f * __builtin_amdgcn_logf(E);  // -lnE
}

__global__ __launch_bounds__(THREADS) void sampler_kernel(
    const float* __restrict__ logits,
    const float* __restrict__ temps,
    unsigned long long* __restrict__ ws) {
    const int g = blockIdx.x;
    const int b = g / SPLIT;
    const int q = g - b * SPLIT;
    const float invT = 1.0f / temps[b];
    const float* rowp = logits + (size_t)b * ROW + (size_t)q * CHUNK;
    const uint32_t cbase = (uint32_t)b * (uint32_t)ROW + (uint32_t)q * CHUNK;

    float best_s = -INFINITY;
    uint32_t best_v = 0u;
    const int tid = threadIdx.x;

#pragma unroll 1
    for (int t = 0; t < ITERS; ++t) {
        const int vl = t * THREADS * 8 + tid * 8;  // 8-aligned
        const float4 xa = *reinterpret_cast<const float4*>(rowp + vl);
        const float4 xb = *reinterpret_cast<const float4*>(rowp + vl + 4);
        const float xs[8] = {xa.x, xa.y, xa.z, xa.w, xb.x, xb.y, xb.z, xb.w};

        uint32_t bits[8];
        threefry8_xor(cbase + (uint32_t)vl, bits);

        float s[8];
#pragma unroll
        for (int j = 0; j < 8; ++j)
            s[j] = fmaf(xs[j], invT, neg_log_exp_noise(bits[j]));

        const uint32_t vb = (uint32_t)(q * CHUNK + vl);
#pragma unroll
        for (int j = 0; j < 8; ++j) {
            // vl 8-aligned -> v = vb | j
            if (s[j] > best_s) { best_s = s[j]; best_v = vb | (uint32_t)j; }
        }
    }

    // pack (orderable(score) << 32) | ~v ; max-reduce; ties -> smallest v
    unsigned long long best =
        ((unsigned long long)f2o(best_s) << 32) | (uint32_t)(~best_v);

#pragma unroll
    for (int off = 32; off >= 1; off >>= 1) {
        const unsigned long long o = __shfl_xor(best, off);
        best = (o > best) ? o : best;
    }

    __shared__ unsigned long long sbest[WAVES];
    const int lane = tid & 63;
    const int wid = tid >> 6;
    if (lane == 0) sbest[wid] = best;
    __syncthreads();

    if (tid == 0) {
        unsigned long long r = sbest[0];
#pragma unroll
        for (int w = 1; w < WAVES; ++w) r = (sbest[w] > r) ? sbest[w] : r;
        ws[g] = r;
    }
}

__global__ __launch_bounds__(BB) void combine_kernel(
    const unsigned long long* __restrict__ ws, int* __restrict__ out) {
    const int b = threadIdx.x;
    const unsigned long long* p = ws + b * SPLIT;
    unsigned long long r = p[0];
#pragma unroll
    for (int w = 1; w < SPLIT; ++w) r = (p[w] > r) ? p[w] : r;
    out[b] = (int)(~(uint32_t)(r & 0xFFFFFFFFull));
}

extern "C" void kernel_launch(void* const* d_in, const int* in_sizes, int n_in,
                              void* d_out, int out_size, void* d_ws, size_t ws_size,
                              hipStream_t stream) {
    const float* logits = (const float*)d_in[0];
    const float* temps = (const float*)d_in[1];
    int* out = (int*)d_out;
    unsigned long long* ws = (unsigned long long*)d_ws;

    hipLaunchKernelGGL(sampler_kernel, dim3(GRID), dim3(THREADS), 0, stream,
                       logits, temps, ws);
    hipLaunchKernelGGL(combine_kernel, dim3(1), dim3(BB), 0, stream, ws, out);
}

// Round 5
// 92.947 us; speedup vs baseline: 1.2654x; 1.2654x over previous
//
#include <hip/hip_runtime.h>
#include <stdint.h>
#include <math.h>

#define BB 256
#define ROW 128000
#define SPLIT 4
#define CHUNK (ROW / SPLIT)        // 32000
#define THREADS 512                // 8 waves -> 4 blocks/CU = 32 waves/CU
#define WAVES (THREADS / 64)
#define EPB (THREADS * 8)          // 4096 elems per iter
#define ITERS ((CHUNK + EPB - 1) / EPB)  // 8 (last partial: 416/512 threads)
#define GRID (BB * SPLIT)          // 1024 = 4 per CU exactly

#define TF_K2 0x1BD11BF0u          // 0x1BD11BDA ^ 0 ^ 42

__device__ __forceinline__ uint32_t rotl32(uint32_t x, int r) {
    return __builtin_amdgcn_alignbit(x, x, 32 - r);  // v_alignbit_b32
}

// Threefry-2x32, key=(0,42), counter (0, c+j) for j=0..7, output o0^o1
// (JAX partitionable threefry — bit-exact, absmax 0.0 through R4).
// Injections folded into v_add3_u32; round 1 exploits x0_init = 0.
__device__ __forceinline__ void threefry8_xor(uint32_t c, uint32_t bits[8]) {
    uint32_t x0[8], x1[8];
#pragma unroll
    for (int j = 0; j < 8; ++j) x1[j] = c + (uint32_t)j + 42u;

    // round 1: x0 = 0 + x1
#pragma unroll
    for (int j = 0; j < 8; ++j) {
        x0[j] = x1[j];
        x1[j] = rotl32(x1[j], 13) ^ x0[j];
    }

#define RND(r)                                        \
    do {                                              \
        _Pragma("unroll")                             \
        for (int j = 0; j < 8; ++j) {                 \
            x0[j] += x1[j];                           \
            x1[j] = rotl32(x1[j], (r)) ^ x0[j];       \
        }                                             \
    } while (0)
// injected round: x1 += B; x0 = x0 + A + x1 (v_add3); rotate/xor
#define RNDI(r, A, B)                                 \
    do {                                              \
        _Pragma("unroll")                             \
        for (int j = 0; j < 8; ++j) {                 \
            x1[j] += (B);                             \
            x0[j] = x0[j] + (A) + x1[j];              \
            x1[j] = rotl32(x1[j], (r)) ^ x0[j];       \
        }                                             \
    } while (0)

    RND(15); RND(26); RND(6);
    RNDI(17, 42u, TF_K2 + 1u);
    RND(29); RND(16); RND(24);
    RNDI(13, TF_K2, 2u);
    RND(15); RND(26); RND(6);
    RNDI(17, 0u, 45u);
    RND(29); RND(16); RND(24);
    RNDI(13, 42u, TF_K2 + 4u);
    RND(15); RND(26); RND(6);

#undef RND
#undef RNDI

#pragma unroll
    for (int j = 0; j < 8; ++j) bits[j] = (x0[j] + TF_K2) ^ (x1[j] + 5u);
}

// order-preserving float -> uint32 map (final reduction only)
__device__ __forceinline__ uint32_t f2o(float f) {
    uint32_t u = __float_as_uint(f);
    return (u & 0x80000000u) ? ~u : (u | 0x80000000u);
}

// -ln(E), E = max(-log1p(-u), 1e-10), u = (bits>>9)*2^-23 exactly.
// Series path for u < 2^-5 protects relative precision near m=1
// (winners live at tiny u -> large -lnE; must stay accurate).
__device__ __forceinline__ float neg_log_exp_noise(uint32_t bits) {
    const float uf = __uint_as_float(0x3F800000u | (bits >> 9));  // 1+u
    const float u = uf - 1.0f;   // exact
    const float m = 2.0f - uf;   // exact 1-u
    const float lg_m = __builtin_amdgcn_logf(m);       // log2(1-u)
    const float E_main = -0.69314718055994530942f * lg_m;
    // 4-term series, u < 2^-5: rel err ~u^4/5 < 2e-7
    const float E_ser =
        u * fmaf(u, fmaf(u, fmaf(u, 0.25f, 0.33333333333f), 0.5f), 1.0f);
    float E = (u < 0.03125f) ? E_ser : E_main;
    E = fmaxf(E, 1e-10f);  // only u==0 hits this (matches ref clamp)
    return -0.69314718055994530942f * __builtin_amdgcn_logf(E);  // -lnE
}

__global__ __launch_bounds__(THREADS, 8) void sampler_kernel(
    const float* __restrict__ logits,
    const float* __restrict__ temps,
    unsigned long long* __restrict__ ws) {
    const int g = blockIdx.x;
    const int b = g >> 2;        // row
    const int q = g & 3;         // quarter
    const float invT = 1.0f / temps[b];
    const float* rowp = logits + (size_t)b * ROW + (size_t)q * CHUNK;
    const uint32_t cbase = (uint32_t)b * (uint32_t)ROW + (uint32_t)q * CHUNK;

    float best_s = -INFINITY;
    uint32_t best_v = 0u;
    const int tid = threadIdx.x;

#pragma unroll 1
    for (int t = 0; t < ITERS; ++t) {
        const int vl = t * EPB + tid * 8;  // 8-aligned
        if (vl < CHUNK) {
            const float4 xa = *reinterpret_cast<const float4*>(rowp + vl);
            const float4 xb = *reinterpret_cast<const float4*>(rowp + vl + 4);
            const float xs[8] = {xa.x, xa.y, xa.z, xa.w, xb.x, xb.y, xb.z, xb.w};

            uint32_t bits[8];
            threefry8_xor(cbase + (uint32_t)vl, bits);

            float s[8];
#pragma unroll
            for (int j = 0; j < 8; ++j)
                s[j] = fmaf(xs[j], invT, neg_log_exp_noise(bits[j]));

            const uint32_t vb = (uint32_t)(q * CHUNK + vl);
#pragma unroll
            for (int j = 0; j < 8; ++j) {
                // vl 8-aligned -> v = vb | j
                if (s[j] > best_s) { best_s = s[j]; best_v = vb | (uint32_t)j; }
            }
        }
    }

    // pack (orderable(score) << 32) | ~v ; max-reduce; ties -> smallest v
    unsigned long long best =
        ((unsigned long long)f2o(best_s) << 32) | (uint32_t)(~best_v);

#pragma unroll
    for (int off = 32; off >= 1; off >>= 1) {
        const unsigned long long o = __shfl_xor(best, off);
        best = (o > best) ? o : best;
    }

    __shared__ unsigned long long sbest[WAVES];
    const int lane = tid & 63;
    const int wid = tid >> 6;
    if (lane == 0) sbest[wid] = best;
    __syncthreads();

    if (tid == 0) {
        unsigned long long r = sbest[0];
#pragma unroll
        for (int w = 1; w < WAVES; ++w) r = (sbest[w] > r) ? sbest[w] : r;
        ws[g] = r;
    }
}

__global__ __launch_bounds__(BB) void combine_kernel(
    const unsigned long long* __restrict__ ws, int* __restrict__ out) {
    const int b = threadIdx.x;
    const unsigned long long* p = ws + b * SPLIT;
    unsigned long long r = p[0];
#pragma unroll
    for (int w = 1; w < SPLIT; ++w) r = (p[w] > r) ? p[w] : r;
    out[b] = (int)(~(uint32_t)(r & 0xFFFFFFFFull));
}

extern "C" void kernel_launch(void* const* d_in, const int* in_sizes, int n_in,
                              void* d_out, int out_size, void* d_ws, size_t ws_size,
                              hipStream_t stream) {
    const float* logits = (const float*)d_in[0];
    const float* temps = (const float*)d_in[1];
    int* out = (int*)d_out;
    unsigned long long* ws = (unsigned long long*)d_ws;

    hipLaunchKernelGGL(sampler_kernel, dim3(GRID), dim3(THREADS), 0, stream,
                       logits, temps, ws);
    hipLaunchKernelGGL(combine_kernel, dim3(1), dim3(BB), 0, stream, ws, out);
}

// Round 6
// 92.152 us; speedup vs baseline: 1.2763x; 1.0086x over previous
//
#include <hip/hip_runtime.h>
#include <stdint.h>
#include <math.h>

#define BB 256
#define ROW 128000
#define SPLIT 4
#define CHUNK (ROW / SPLIT)        // 32000
#define THREADS 512                // 8 waves -> 4 blocks/CU = 32 waves/CU
#define WAVES (THREADS / 64)
#define EPB (THREADS * 8)          // 4096 elems per iter
#define ITERS ((CHUNK + EPB - 1) / EPB)  // 8 (last partial: 416/512 threads)
#define GRID (BB * SPLIT)          // 1024 = 4 per CU exactly

#define TF_K2 0x1BD11BF0u          // 0x1BD11BDA ^ 0 ^ 42
// series threshold: uf < 1 + 2^-12 (u < 2^-12). P(elem small) = 2^-12
// -> P(512-elem slab has any small) ~ 12.5% -> series block usually skipped.
#define SMALL_C 1.000244140625f

__device__ __forceinline__ uint32_t rotl32(uint32_t x, int r) {
    return __builtin_amdgcn_alignbit(x, x, 32 - r);  // v_alignbit_b32
}

// Threefry-2x32, key=(0,42), counter (0, c+j) for j=0..7, output o0^o1
// (JAX partitionable threefry — bit-exact, absmax 0.0 through R5).
__device__ __forceinline__ void threefry8_xor(uint32_t c, uint32_t bits[8]) {
    uint32_t x0[8], x1[8];
#pragma unroll
    for (int j = 0; j < 8; ++j) x1[j] = c + (uint32_t)j + 42u;

    // round 1: x0 = 0 + x1
#pragma unroll
    for (int j = 0; j < 8; ++j) {
        x0[j] = x1[j];
        x1[j] = rotl32(x1[j], 13) ^ x0[j];
    }

#define RND(r)                                        \
    do {                                              \
        _Pragma("unroll")                             \
        for (int j = 0; j < 8; ++j) {                 \
            x0[j] += x1[j];                           \
            x1[j] = rotl32(x1[j], (r)) ^ x0[j];       \
        }                                             \
    } while (0)
#define RNDI(r, A, B)                                 \
    do {                                              \
        _Pragma("unroll")                             \
        for (int j = 0; j < 8; ++j) {                 \
            x1[j] += (B);                             \
            x0[j] = x0[j] + (A) + x1[j];              \
            x1[j] = rotl32(x1[j], (r)) ^ x0[j];       \
        }                                             \
    } while (0)

    RND(15); RND(26); RND(6);
    RNDI(17, 42u, TF_K2 + 1u);
    RND(29); RND(16); RND(24);
    RNDI(13, TF_K2, 2u);
    RND(15); RND(26); RND(6);
    RNDI(17, 0u, 45u);
    RND(29); RND(16); RND(24);
    RNDI(13, 42u, TF_K2 + 4u);
    RND(15); RND(26); RND(6);

#undef RND
#undef RNDI

#pragma unroll
    for (int j = 0; j < 8; ++j) bits[j] = (x0[j] + TF_K2) ^ (x1[j] + 5u);
}

// order-preserving float -> uint32 map (final reduction only)
__device__ __forceinline__ uint32_t f2o(float f) {
    uint32_t u = __float_as_uint(f);
    return (u & 0x80000000u) ? ~u : (u | 0x80000000u);
}

__global__ __launch_bounds__(THREADS, 8) void sampler_kernel(
    const float* __restrict__ logits,
    const float* __restrict__ temps,
    unsigned long long* __restrict__ ws) {
    const int g = blockIdx.x;
    const int b = g >> 2;        // row
    const int q = g & 3;         // quarter
    const float invT = 1.0f / temps[b];
    const float* rowp = logits + (size_t)b * ROW + (size_t)q * CHUNK;
    const uint32_t cbase = (uint32_t)b * (uint32_t)ROW + (uint32_t)q * CHUNK;

    float best_s = -INFINITY;
    int best_code = 0;           // t*8 + j, reconstructed to v at the end
    const int tid = threadIdx.x;

#pragma unroll 1
    for (int t = 0; t < ITERS; ++t) {
        const int vl = t * EPB + tid * 8;  // 8-aligned
        if (vl < CHUNK) {
            const float4 xa = *reinterpret_cast<const float4*>(rowp + vl);
            const float4 xb = *reinterpret_cast<const float4*>(rowp + vl + 4);
            const float xs[8] = {xa.x, xa.y, xa.z, xa.w, xb.x, xb.y, xb.z, xb.w};

            uint32_t bits[8];
            threefry8_xor(cbase + (uint32_t)vl, bits);

            // u = (bits>>9)*2^-23 exactly; uf = 1+u in [1,2); m = 1-u exact.
            float uf8[8], E8[8];
#pragma unroll
            for (int j = 0; j < 8; ++j) {
                uf8[j] = __uint_as_float(0x3F800000u | (bits[j] >> 9));
                const float m = 2.0f - uf8[j];
                // E = -log1p(-u) = -ln2 * log2(m), hw log (quarter-rate)
                E8[j] = -0.69314718055994530942f * __builtin_amdgcn_logf(m);
            }

            // rare fix-up: tiny-u elements need the exact series (hw log2
            // loses relative precision as m -> 1; winners live at tiny u).
            const float mn01 = fminf(fminf(uf8[0], uf8[1]), uf8[2]);
            const float mn34 = fminf(fminf(uf8[3], uf8[4]), uf8[5]);
            const float mn67 = fminf(uf8[6], uf8[7]);
            const float ufmin = fminf(fminf(mn01, mn34), mn67);
            if (__any(ufmin < SMALL_C)) {
#pragma unroll
                for (int j = 0; j < 8; ++j) {
                    const float u = uf8[j] - 1.0f;  // exact
                    const float es = u * fmaf(u, fmaf(u, fmaf(u, 0.25f,
                                     0.33333333333f), 0.5f), 1.0f);
                    E8[j] = (uf8[j] < SMALL_C) ? es : E8[j];
                }
            }

#pragma unroll
            for (int j = 0; j < 8; ++j) {
                const float E = fmaxf(E8[j], 1e-10f);  // ref clamp (u==0 case)
                const float gn = -0.69314718055994530942f *
                                 __builtin_amdgcn_logf(E);  // -lnE
                const float s = fmaf(xs[j], invT, gn);
                if (s > best_s) { best_s = s; best_code = t * 8 + j; }
            }
        }
    }

    // reconstruct vocabulary index from (iter, j) code
    const uint32_t best_v = (uint32_t)(q * CHUNK + tid * 8) +
                            (uint32_t)((best_code >> 3) * EPB) +
                            (uint32_t)(best_code & 7);

    // pack (orderable(score) << 32) | ~v ; max-reduce; ties -> smallest v
    unsigned long long best =
        ((unsigned long long)f2o(best_s) << 32) | (uint32_t)(~best_v);

#pragma unroll
    for (int off = 32; off >= 1; off >>= 1) {
        const unsigned long long o = __shfl_xor(best, off);
        best = (o > best) ? o : best;
    }

    __shared__ unsigned long long sbest[WAVES];
    const int lane = tid & 63;
    const int wid = tid >> 6;
    if (lane == 0) sbest[wid] = best;
    __syncthreads();

    if (tid == 0) {
        unsigned long long r = sbest[0];
#pragma unroll
        for (int w = 1; w < WAVES; ++w) r = (sbest[w] > r) ? sbest[w] : r;
        ws[g] = r;
    }
}

__global__ __launch_bounds__(BB) void combine_kernel(
    const unsigned long long* __restrict__ ws, int* __restrict__ out) {
    const int b = threadIdx.x;
    const unsigned long long* p = ws + b * SPLIT;
    unsigned long long r = p[0];
#pragma unroll
    for (int w = 1; w < SPLIT; ++w) r = (p[w] > r) ? p[w] : r;
    out[b] = (int)(~(uint32_t)(r & 0xFFFFFFFFull));
}

extern "C" void kernel_launch(void* const* d_in, const int* in_sizes, int n_in,
                              void* d_out, int out_size, void* d_ws, size_t ws_size,
                              hipStream_t stream) {
    const float* logits = (const float*)d_in[0];
    const float* temps = (const float*)d_in[1];
    int* out = (int*)d_out;
    unsigned long long* ws = (unsigned long long*)d_ws;

    hipLaunchKernelGGL(sampler_kernel, dim3(GRID), dim3(THREADS), 0, stream,
                       logits, temps, ws);
    hipLaunchKernelGGL(combine_kernel, dim3(1), dim3(BB), 0, stream, ws, out);
}

// Round 7
// 91.318 us; speedup vs baseline: 1.2880x; 1.0091x over previous
//
#include <hip/hip_runtime.h>
#include <stdint.h>
#include <math.h>

#define BB 256
#define ROW 128000
#define SPLIT 4
#define CHUNK (ROW / SPLIT)        // 32000
#define THREADS 512                // 8 waves
#define WAVES (THREADS / 64)
#define EPB (THREADS * 8)          // 4096 elems per iter
#define ITERS ((CHUNK + EPB - 1) / EPB)  // 8 (last partial: 416/512 threads)
#define GRID (BB * SPLIT)          // 1024 = 4 per CU exactly

#define TF_K2 0x1BD11BF0u          // 0x1BD11BDA ^ 0 ^ 42
// series threshold: uf < 1 + 2^-12 (u < 2^-12); slab takes fix-up ~12.5%.
#define SMALL_C 1.000244140625f
// clamp in L = E/ln2 domain: 1e-10 / ln2
#define MIN_L 1.4426950408889634e-10f

__device__ __forceinline__ uint32_t rotl32(uint32_t x, int r) {
    return __builtin_amdgcn_alignbit(x, x, 32 - r);  // v_alignbit_b32
}

// Threefry-2x32, key=(0,42), counter (0, c+j) for j=0..7, output o0^o1
// (JAX partitionable threefry — bit-exact, absmax 0.0 through R6).
__device__ __forceinline__ void threefry8_xor(uint32_t c, uint32_t bits[8]) {
    uint32_t x0[8], x1[8];
#pragma unroll
    for (int j = 0; j < 8; ++j) x1[j] = c + (uint32_t)j + 42u;

    // round 1: x0 = 0 + x1
#pragma unroll
    for (int j = 0; j < 8; ++j) {
        x0[j] = x1[j];
        x1[j] = rotl32(x1[j], 13) ^ x0[j];
    }

#define RND(r)                                        \
    do {                                              \
        _Pragma("unroll")                             \
        for (int j = 0; j < 8; ++j) {                 \
            x0[j] += x1[j];                           \
            x1[j] = rotl32(x1[j], (r)) ^ x0[j];       \
        }                                             \
    } while (0)
#define RNDI(r, A, B)                                 \
    do {                                              \
        _Pragma("unroll")                             \
        for (int j = 0; j < 8; ++j) {                 \
            x1[j] += (B);                             \
            x0[j] = x0[j] + (A) + x1[j];              \
            x1[j] = rotl32(x1[j], (r)) ^ x0[j];       \
        }                                             \
    } while (0)

    RND(15); RND(26); RND(6);
    RNDI(17, 42u, TF_K2 + 1u);
    RND(29); RND(16); RND(24);
    RNDI(13, TF_K2, 2u);
    RND(15); RND(26); RND(6);
    RNDI(17, 0u, 45u);
    RND(29); RND(16); RND(24);
    RNDI(13, 42u, TF_K2 + 4u);
    RND(15); RND(26); RND(6);

#undef RND
#undef RNDI

#pragma unroll
    for (int j = 0; j < 8; ++j) bits[j] = (x0[j] + TF_K2) ^ (x1[j] + 5u);
}

// order-preserving float -> uint32 map (final reduction only)
__device__ __forceinline__ uint32_t f2o(float f) {
    uint32_t u = __float_as_uint(f);
    return (u & 0x80000000u) ? ~u : (u | 0x80000000u);
}

__global__ __launch_bounds__(THREADS, 4) void sampler_kernel(
    const float* __restrict__ logits,
    const float* __restrict__ temps,
    unsigned long long* __restrict__ ws) {
    const int g = blockIdx.x;
    const int b = g >> 2;        // row
    const int q = g & 3;         // quarter
    // score in log2 domain: s = x/(T*ln2) - log2(L); order == ref order
    const float invT2 = 1.0f / (temps[b] * 0.69314718055994530942f);
    const float* rowp = logits + (size_t)b * ROW + (size_t)q * CHUNK;
    const uint32_t cbase = (uint32_t)b * (uint32_t)ROW + (uint32_t)q * CHUNK;

    float best_s = -INFINITY;
    int best_code = 0;           // t*8 + j, reconstructed to v at the end
    const int tid = threadIdx.x;

#pragma unroll 1
    for (int t = 0; t < ITERS; ++t) {
        const int vl = t * EPB + tid * 8;  // 8-aligned
        if (vl < CHUNK) {
            const float4 xa = *reinterpret_cast<const float4*>(rowp + vl);
            const float4 xb = *reinterpret_cast<const float4*>(rowp + vl + 4);
            const float xs[8] = {xa.x, xa.y, xa.z, xa.w, xb.x, xb.y, xb.z, xb.w};

            uint32_t bits[8];
            threefry8_xor(cbase + (uint32_t)vl, bits);

            // u = (bits>>9)*2^-23 exactly; uf = 1+u in [1,2); m = 1-u exact.
            // L8 holds -(E/ln2):  main path log2(m) (<=0), series path -es2.
            float uf8[8], L8[8];
#pragma unroll
            for (int j = 0; j < 8; ++j) {
                uf8[j] = __uint_as_float(0x3F800000u | (bits[j] >> 9));
                const float m = 2.0f - uf8[j];
                L8[j] = __builtin_amdgcn_logf(m);  // log2(1-u), trans pipe
            }

            // rare fix-up: tiny-u elements need the exact series (hw log2
            // relative precision near m=1; winners live at tiny u).
            const float mn01 = fminf(fminf(uf8[0], uf8[1]), uf8[2]);
            const float mn34 = fminf(fminf(uf8[3], uf8[4]), uf8[5]);
            const float mn67 = fminf(uf8[6], uf8[7]);
            const float ufmin = fminf(fminf(mn01, mn34), mn67);
            if (__any(ufmin < SMALL_C)) {
#pragma unroll
                for (int j = 0; j < 8; ++j) {
                    const float u = uf8[j] - 1.0f;  // exact
                    // -(1/ln2) * (u + u^2/2 + u^3/3 + u^4/4), sign folded
                    const float es2 = u * fmaf(u, fmaf(u, fmaf(u,
                        -0.3606737602222408f, -0.4808983469629878f),
                        -0.7213475204444817f), -1.4426950408889634f);
                    L8[j] = (uf8[j] < SMALL_C) ? es2 : L8[j];
                }
            }

#pragma unroll
            for (int j = 0; j < 8; ++j) {
                const float Lc = fmaxf(-L8[j], MIN_L);  // neg: input modifier
                const float lg = __builtin_amdgcn_logf(Lc);  // log2(L)
                const float s = fmaf(xs[j], invT2, -lg);
                if (s > best_s) { best_s = s; best_code = t * 8 + j; }
            }
        }
    }

    // reconstruct vocabulary index from (iter, j) code
    const uint32_t best_v = (uint32_t)(q * CHUNK + tid * 8) +
                            (uint32_t)((best_code >> 3) * EPB) +
                            (uint32_t)(best_code & 7);

    // pack (orderable(score) << 32) | ~v ; max-reduce; ties -> smallest v
    unsigned long long best =
        ((unsigned long long)f2o(best_s) << 32) | (uint32_t)(~best_v);

#pragma unroll
    for (int off = 32; off >= 1; off >>= 1) {
        const unsigned long long o = __shfl_xor(best, off);
        best = (o > best) ? o : best;
    }

    __shared__ unsigned long long sbest[WAVES];
    const int lane = tid & 63;
    const int wid = tid >> 6;
    if (lane == 0) sbest[wid] = best;
    __syncthreads();

    if (tid == 0) {
        unsigned long long r = sbest[0];
#pragma unroll
        for (int w = 1; w < WAVES; ++w) r = (sbest[w] > r) ? sbest[w] : r;
        ws[g] = r;
    }
}

__global__ __launch_bounds__(BB) void combine_kernel(
    const unsigned long long* __restrict__ ws, int* __restrict__ out) {
    const int b = threadIdx.x;
    const unsigned long long* p = ws + b * SPLIT;
    unsigned long long r = p[0];
#pragma unroll
    for (int w = 1; w < SPLIT; ++w) r = (p[w] > r) ? p[w] : r;
    out[b] = (int)(~(uint32_t)(r & 0xFFFFFFFFull));
}

extern "C" void kernel_launch(void* const* d_in, const int* in_sizes, int n_in,
                              void* d_out, int out_size, void* d_ws, size_t ws_size,
                              hipStream_t stream) {
    const float* logits = (const float*)d_in[0];
    const float* temps = (const float*)d_in[1];
    int* out = (int*)d_out;
    unsigned long long* ws = (unsigned long long*)d_ws;

    hipLaunchKernelGGL(sampler_kernel, dim3(GRID), dim3(THREADS), 0, stream,
                       logits, temps, ws);
    hipLaunchKernelGGL(combine_kernel, dim3(1), dim3(BB), 0, stream, ws, out);
}

// Round 8
// 87.476 us; speedup vs baseline: 1.3446x; 1.0439x over previous
//
#include <hip/hip_runtime.h>
#include <stdint.h>
#include <math.h>

#define BB 256
#define ROW 128000
#define SPLIT 4
#define CHUNK (ROW / SPLIT)        // 32000
#define THREADS 512                // 8 waves
#define WAVES (THREADS / 64)
#define EPB (THREADS * 8)          // 4096 elems per full iter
#define FULL_ITERS 7               // 7*4096 = 28672
#define ITERS 8                    // + partial (3328 elems, 416 threads)
#define GRID (BB * SPLIT)          // 1024 = 4 per CU exactly

#define TF_K2 0x1BD11BF0u          // 0x1BD11BDA ^ 0 ^ 42
// small-u test on raw bits: u = (bits>>9)*2^-23 < 2^-12  <=>  bits < 2^20
#define SMALL_BITS 0x00100000u
// clamp in L = E/ln2 domain: 1e-10 / ln2 (stored negated in L8)
#define MIN_L 1.4426950408889634e-10f

__device__ __forceinline__ uint32_t rotl32(uint32_t x, int r) {
    return __builtin_amdgcn_alignbit(x, x, 32 - r);  // v_alignbit_b32
}

// Threefry-2x32, key=(0,42), counter (0, c+j) for j=0..7, output o0^o1
// (JAX partitionable threefry — bit-exact, absmax 0.0 through R7).
__device__ __forceinline__ void threefry8_xor(uint32_t c, uint32_t bits[8]) {
    uint32_t x0[8], x1[8];
#pragma unroll
    for (int j = 0; j < 8; ++j) x1[j] = c + (uint32_t)(j + 42);

    // round 1: x0 = 0 + x1
#pragma unroll
    for (int j = 0; j < 8; ++j) {
        x0[j] = x1[j];
        x1[j] = rotl32(x1[j], 13) ^ x0[j];
    }

#define RND(r)                                        \
    do {                                              \
        _Pragma("unroll")                             \
        for (int j = 0; j < 8; ++j) {                 \
            x0[j] += x1[j];                           \
            x1[j] = rotl32(x1[j], (r)) ^ x0[j];       \
        }                                             \
    } while (0)
#define RNDI(r, A, B)                                 \
    do {                                              \
        _Pragma("unroll")                             \
        for (int j = 0; j < 8; ++j) {                 \
            x1[j] += (B);                             \
            x0[j] = x0[j] + (A) + x1[j];              \
            x1[j] = rotl32(x1[j], (r)) ^ x0[j];       \
        }                                             \
    } while (0)

    RND(15); RND(26); RND(6);
    RNDI(17, 42u, TF_K2 + 1u);
    RND(29); RND(16); RND(24);
    RNDI(13, TF_K2, 2u);
    RND(15); RND(26); RND(6);
    RNDI(17, 0u, 45u);
    RND(29); RND(16); RND(24);
    RNDI(13, 42u, TF_K2 + 4u);
    RND(15); RND(26); RND(6);

#undef RND
#undef RNDI

#pragma unroll
    for (int j = 0; j < 8; ++j) bits[j] = (x0[j] + TF_K2) ^ (x1[j] + 5u);
}

// order-preserving float -> uint32 map (final reduction only)
__device__ __forceinline__ uint32_t f2o(float f) {
    uint32_t u = __float_as_uint(f);
    return (u & 0x80000000u) ? ~u : (u | 0x80000000u);
}

// one slab: 8 elements for this thread at counter cb, logits in xs[8].
// maintains (best_s, best_code); code = t*8+j.
__device__ __forceinline__ void do_slab(const float xs[8], uint32_t cb, int t,
                                        float invT2, float& best_s,
                                        int& best_code) {
    uint32_t bits[8];
    threefry8_xor(cb, bits);

    // L8 = -(E/ln2): main path log2(1-u) <= -3.5e-4 (never needs clamp).
    float L8[8];
#pragma unroll
    for (int j = 0; j < 8; ++j) {
        const float uf = __uint_as_float(0x3F800000u | (bits[j] >> 9));
        L8[j] = __builtin_amdgcn_logf(2.0f - uf);  // log2(1-u), trans pipe
    }

    // rare fix-up: tiny u (bits < 2^20, P=2^-12/elem) -> exact series +
    // the 1e-10 clamp (only u==0 can clamp, and it lands here).
    const uint32_t b01 = min(min(bits[0], bits[1]), bits[2]);
    const uint32_t b34 = min(min(bits[3], bits[4]), bits[5]);
    const uint32_t b67 = min(bits[6], bits[7]);
    const uint32_t bmin = min(min(b01, b34), b67);
    if (__any(bmin < SMALL_BITS)) {
#pragma unroll
        for (int j = 0; j < 8; ++j) {
            const float uf = __uint_as_float(0x3F800000u | (bits[j] >> 9));
            const float u = uf - 1.0f;  // exact
            // -(1/ln2) * (u + u^2/2 + u^3/3 + u^4/4), sign pre-folded
            const float es2 = u * fmaf(u, fmaf(u, fmaf(u,
                -0.3606737602222408f, -0.4808983469629878f),
                -0.7213475204444817f), -1.4426950408889634f);
            const float es2c = fminf(es2, -MIN_L);  // clamp (u==0 -> -MIN_L)
            L8[j] = (bits[j] < SMALL_BITS) ? es2c : L8[j];
        }
    }

#pragma unroll
    for (int j = 0; j < 8; ++j) {
        const float lg = __builtin_amdgcn_logf(-L8[j]);  // neg mod is free
        const float s = fmaf(xs[j], invT2, -lg);
        if (s > best_s) { best_s = s; best_code = t * 8 + j; }
    }
}

__global__ __launch_bounds__(THREADS, 4) void sampler_kernel(
    const float* __restrict__ logits,
    const float* __restrict__ temps,
    unsigned long long* __restrict__ ws) {
    const int g = blockIdx.x;
    const int b = g >> 2;        // row
    const int q = g & 3;         // quarter
    // score in log2 domain: s = x/(T*ln2) - log2(L); order == ref order
    const float invT2 = 1.0f / (temps[b] * 0.69314718055994530942f);
    const float* rowp = logits + (size_t)b * ROW + (size_t)q * CHUNK;
    const uint32_t cbase = (uint32_t)b * (uint32_t)ROW + (uint32_t)q * CHUNK;

    float best_s = -INFINITY;
    int best_code = 0;           // t*8 + j, reconstructed to v at the end
    const int tid = threadIdx.x;

#pragma unroll 1
    for (int t = 0; t < FULL_ITERS; ++t) {
        const int vl = t * EPB + tid * 8;  // 8-aligned, always in range
        const float4 xa = *reinterpret_cast<const float4*>(rowp + vl);
        const float4 xb = *reinterpret_cast<const float4*>(rowp + vl + 4);
        const float xs[8] = {xa.x, xa.y, xa.z, xa.w, xb.x, xb.y, xb.z, xb.w};
        do_slab(xs, cbase + (uint32_t)vl, t, invT2, best_s, best_code);
    }
    {   // peeled partial iteration: 3328 elems -> threads 0..415
        const int vl = FULL_ITERS * EPB + tid * 8;
        if (vl < CHUNK) {
            const float4 xa = *reinterpret_cast<const float4*>(rowp + vl);
            const float4 xb = *reinterpret_cast<const float4*>(rowp + vl + 4);
            const float xs[8] = {xa.x, xa.y, xa.z, xa.w,
                                 xb.x, xb.y, xb.z, xb.w};
            do_slab(xs, cbase + (uint32_t)vl, FULL_ITERS, invT2, best_s,
                    best_code);
        }
    }

    // reconstruct vocabulary index from (iter, j) code
    const uint32_t best_v = (uint32_t)(q * CHUNK + tid * 8) +
                            (uint32_t)((best_code >> 3) * EPB) +
                            (uint32_t)(best_code & 7);

    // pack (orderable(score) << 32) | ~v ; max-reduce; ties -> smallest v
    unsigned long long best =
        ((unsigned long long)f2o(best_s) << 32) | (uint32_t)(~best_v);

#pragma unroll
    for (int off = 32; off >= 1; off >>= 1) {
        const unsigned long long o = __shfl_xor(best, off);
        best = (o > best) ? o : best;
    }

    __shared__ unsigned long long sbest[WAVES];
    const int lane = tid & 63;
    const int wid = tid >> 6;
    if (lane == 0) sbest[wid] = best;
    __syncthreads();

    if (tid == 0) {
        unsigned long long r = sbest[0];
#pragma unroll
        for (int w = 1; w < WAVES; ++w) r = (sbest[w] > r) ? sbest[w] : r;
        ws[g] = r;
    }
}

__global__ __launch_bounds__(BB) void combine_kernel(
    const unsigned long long* __restrict__ ws, int* __restrict__ out) {
    const int b = threadIdx.x;
    const unsigned long long* p = ws + b * SPLIT;
    unsigned long long r = p[0];
#pragma unroll
    for (int w = 1; w < SPLIT; ++w) r = (p[w] > r) ? p[w] : r;
    out[b] = (int)(~(uint32_t)(r & 0xFFFFFFFFull));
}

extern "C" void kernel_launch(void* const* d_in, const int* in_sizes, int n_in,
                              void* d_out, int out_size, void* d_ws, size_t ws_size,
                              hipStream_t stream) {
    const float* logits = (const float*)d_in[0];
    const float* temps = (const float*)d_in[1];
    int* out = (int*)d_out;
    unsigned long long* ws = (unsigned long long*)d_ws;

    hipLaunchKernelGGL(sampler_kernel, dim3(GRID), dim3(THREADS), 0, stream,
                       logits, temps, ws);
    hipLaunchKernelGGL(combine_kernel, dim3(1), dim3(BB), 0, stream, ws, out);
}